// Round 1
// baseline (416.710 us; speedup 1.0000x reference)
//
#include <hip/hip_runtime.h>
#include <math.h>

// Problem constants (verified against in_sizes at launch):
//   N=5000 nodes, E=80000 edges, C=32, H=W=8  -> CHW = 2048 floats/node
#define CCH   32
#define HWPIX 64
#define CHW   2048
#define EDGE_CHUNK 64

__device__ __forceinline__ float gelu_f(float x) {
    // exact GELU: x * Phi(x) = 0.5 * x * (1 + erf(x / sqrt(2)))
    return 0.5f * x * (1.0f + erff(x * 0.7071067811865475f));
}

// ---------------- CSR build over dst ----------------

__global__ __launch_bounds__(256) void zero_cnt_kernel(int* cnt, int n) {
    int i = blockIdx.x * 256 + threadIdx.x;
    if (i < n) cnt[i] = 0;
}

__global__ __launch_bounds__(256) void hist_kernel(const int* __restrict__ dst,
                                                   int* cnt, int ne) {
    int i = blockIdx.x * 256 + threadIdx.x;
    if (i < ne) atomicAdd(&cnt[dst[i]], 1);
}

// Single-block exclusive scan over nn (<=8192) counts; writes offs[0..nn] and cursor copy.
__global__ __launch_bounds__(256) void scan_kernel(const int* __restrict__ cnt,
                                                   int* __restrict__ offs,
                                                   int* __restrict__ cursor,
                                                   int nn) {
    __shared__ int part[256];
    int t = threadIdx.x;
    int per = (nn + 255) >> 8;
    if (per > 32) per = 32;  // local[] bound; nn=5000 -> per=20
    int base = t * per;
    int local[32];
    int sum = 0;
    for (int i = 0; i < per; i++) {
        int idx = base + i;
        int v = (idx < nn) ? cnt[idx] : 0;
        local[i] = sum;  // exclusive within this thread's span
        sum += v;
    }
    part[t] = sum;
    __syncthreads();
    // Hillis-Steele inclusive scan of per-thread sums
    int acc = sum;
    for (int d = 1; d < 256; d <<= 1) {
        int tv = (t >= d) ? part[t - d] : 0;
        __syncthreads();
        acc += tv;
        part[t] = acc;
        __syncthreads();
    }
    int excl = acc - sum;
    for (int i = 0; i < per; i++) {
        int idx = base + i;
        if (idx < nn) {
            int o = excl + local[i];
            offs[idx] = o;
            cursor[idx] = o;
        }
    }
    if (t == 255) offs[nn] = acc;  // == ne
}

__global__ __launch_bounds__(256) void scatter_kernel(const int* __restrict__ dst,
                                                      int* cursor,
                                                      int* __restrict__ eid, int ne) {
    int i = blockIdx.x * 256 + threadIdx.x;
    if (i < ne) {
        int p = atomicAdd(&cursor[dst[i]], 1);
        eid[p] = i;
    }
}

// ---------------- per-node 3x3 conv (no bias; bias applied post-scale) ----------------
// out[n,co,y,x] = sum_{ci,kh,kw} h[n,ci,y+kh-1,x+kw-1] * w[co,ci,kh,kw]
// One block per node. thread = co*8 + y, computes the 8 x-values of one row.
__global__ __launch_bounds__(256) void conv_kernel(const float* __restrict__ h,
                                                   const float* __restrict__ w,
                                                   float* __restrict__ convh) {
    __shared__ float sin_[CCH * HWPIX];      // 8 KB input tile
    __shared__ float sw[CCH * CCH * 9];      // 36 KB weights
    int n = blockIdx.x;
    const float* hn = h + (size_t)n * CHW;
    for (int i = threadIdx.x; i < CCH * HWPIX; i += 256) sin_[i] = hn[i];
    for (int i = threadIdx.x; i < CCH * CCH * 9; i += 256) sw[i] = w[i];
    __syncthreads();

    int co = threadIdx.x >> 3;
    int y  = threadIdx.x & 7;
    float acc[8];
#pragma unroll
    for (int x = 0; x < 8; x++) acc[x] = 0.f;

    for (int ci = 0; ci < CCH; ci++) {
        const float* srow = sin_ + ci * HWPIX;
        const float* wp = sw + (co * CCH + ci) * 9;
#pragma unroll
        for (int kh = 0; kh < 3; kh++) {
            int yy = y + kh - 1;
            if (yy < 0 || yy > 7) continue;  // zero pad rows
            const float* r = srow + yy * 8;
            float w0 = wp[kh * 3 + 0], w1 = wp[kh * 3 + 1], w2 = wp[kh * 3 + 2];
            float v[8];
#pragma unroll
            for (int x = 0; x < 8; x++) v[x] = r[x];
#pragma unroll
            for (int x = 0; x < 8; x++) {
                float s = w1 * v[x];
                if (x > 0) s += w0 * v[x - 1];   // kw=0 hits x-1; zero pad at x=0
                if (x < 7) s += w2 * v[x + 1];   // kw=2 hits x+1; zero pad at x=7
                acc[x] += s;
            }
        }
    }
    float* op = convh + (size_t)n * CHW + co * HWPIX + y * 8;
#pragma unroll
    for (int x = 0; x < 8; x++) op[x] = acc[x];
}

// ---------------- gather + min/max + GELU epilogue ----------------
// One block per destination node. Each thread owns 8 output elements as two
// float4 spans: A = [4t, 4t+4), B = [1024+4t, 1024+4t+4).
// Track min/max of pre-activation e_k*convh[src_k]; GELU is quasiconvex so
// max_k GELU(x_k + b) = max(GELU(xmin + b), GELU(xmax + b)).
__global__ __launch_bounds__(256) void gather_max_kernel(
    const float* __restrict__ convh, const float* __restrict__ e,
    const int* __restrict__ src, const float* __restrict__ bias,
    const int* __restrict__ offs, const int* __restrict__ eid,
    float* __restrict__ out) {
    __shared__ int   s_src[EDGE_CHUNK];
    __shared__ float s_w[EDGE_CHUNK];
    int n = blockIdx.x;
    int t = threadIdx.x;
    int beg = offs[n], end = offs[n + 1];

    const float NEG = -3.402823466e+38f, POS = 3.402823466e+38f;
    float mx[8], mn[8];
#pragma unroll
    for (int i = 0; i < 8; i++) { mx[i] = NEG; mn[i] = POS; }

    for (int cs = beg; cs < end; cs += EDGE_CHUNK) {
        int m = end - cs;
        if (m > EDGE_CHUNK) m = EDGE_CHUNK;
        __syncthreads();  // protect s_src/s_w from previous iteration readers
        if (t < m) {
            int k = eid[cs + t];
            s_src[t] = src[k];
            s_w[t]   = e[k];
        }
        __syncthreads();
        for (int j = 0; j < m; j++) {
            const float* bp = convh + (size_t)s_src[j] * CHW;
            float wgt = s_w[j];
            float4 a = ((const float4*)bp)[t];
            float4 b = ((const float4*)bp)[256 + t];
            float p0 = wgt * a.x, p1 = wgt * a.y, p2 = wgt * a.z, p3 = wgt * a.w;
            float p4 = wgt * b.x, p5 = wgt * b.y, p6 = wgt * b.z, p7 = wgt * b.w;
            mx[0] = fmaxf(mx[0], p0); mn[0] = fminf(mn[0], p0);
            mx[1] = fmaxf(mx[1], p1); mn[1] = fminf(mn[1], p1);
            mx[2] = fmaxf(mx[2], p2); mn[2] = fminf(mn[2], p2);
            mx[3] = fmaxf(mx[3], p3); mn[3] = fminf(mn[3], p3);
            mx[4] = fmaxf(mx[4], p4); mn[4] = fminf(mn[4], p4);
            mx[5] = fmaxf(mx[5], p5); mn[5] = fminf(mn[5], p5);
            mx[6] = fmaxf(mx[6], p6); mn[6] = fminf(mn[6], p6);
            mx[7] = fmaxf(mx[7], p7); mn[7] = fminf(mn[7], p7);
        }
    }

    // bias per channel: elem A = 4t -> ch t>>4 ; elem B = 1024+4t -> ch 16+(t>>4)
    float bA = bias[t >> 4];
    float bB = bias[16 + (t >> 4)];
    float4 rA, rB;
    rA.x = fmaxf(gelu_f(mx[0] + bA), gelu_f(mn[0] + bA));
    rA.y = fmaxf(gelu_f(mx[1] + bA), gelu_f(mn[1] + bA));
    rA.z = fmaxf(gelu_f(mx[2] + bA), gelu_f(mn[2] + bA));
    rA.w = fmaxf(gelu_f(mx[3] + bA), gelu_f(mn[3] + bA));
    rB.x = fmaxf(gelu_f(mx[4] + bB), gelu_f(mn[4] + bB));
    rB.y = fmaxf(gelu_f(mx[5] + bB), gelu_f(mn[5] + bB));
    rB.z = fmaxf(gelu_f(mx[6] + bB), gelu_f(mn[6] + bB));
    rB.w = fmaxf(gelu_f(mx[7] + bB), gelu_f(mn[7] + bB));

    float* op = out + (size_t)n * CHW;
    ((float4*)op)[t] = rA;
    ((float4*)op)[256 + t] = rB;
}

extern "C" void kernel_launch(void* const* d_in, const int* in_sizes, int n_in,
                              void* d_out, int out_size, void* d_ws, size_t ws_size,
                              hipStream_t stream) {
    const float* h      = (const float*)d_in[0];
    const float* e      = (const float*)d_in[1];
    const float* conv_w = (const float*)d_in[2];
    const float* conv_b = (const float*)d_in[3];
    const int*   src    = (const int*)d_in[4];
    const int*   dst    = (const int*)d_in[5];
    int nn = in_sizes[0] / CHW;  // 5000
    int ne = in_sizes[1];        // 80000

    // workspace layout (~41.3 MB)
    float* convh  = (float*)d_ws;                       // nn*CHW floats
    int*   cnt    = (int*)(convh + (size_t)nn * CHW);   // nn
    int*   offs   = cnt + nn;                           // nn+1
    int*   cursor = offs + nn + 1;                      // nn
    int*   eid    = cursor + nn;                        // ne

    zero_cnt_kernel<<<(nn + 255) / 256, 256, 0, stream>>>(cnt, nn);
    hist_kernel<<<(ne + 255) / 256, 256, 0, stream>>>(dst, cnt, ne);
    scan_kernel<<<1, 256, 0, stream>>>(cnt, offs, cursor, nn);
    scatter_kernel<<<(ne + 255) / 256, 256, 0, stream>>>(dst, cursor, eid, ne);
    conv_kernel<<<nn, 256, 0, stream>>>(h, conv_w, convh);
    gather_max_kernel<<<nn, 256, 0, stream>>>(convh, e, src, conv_b, offs, eid,
                                              (float*)d_out);
}

// Round 2
// 284.571 us; speedup vs baseline: 1.4643x; 1.4643x over previous
//
#include <hip/hip_runtime.h>
#include <math.h>

// N=5000 nodes, E=80000 edges, C=32, H=W=8  -> CHW = 2048 floats/node
#define CCH   32
#define HWPIX 64
#define CHW   2048
#define EDGE_CHUNK 64

__device__ __forceinline__ float gelu_f(float x) {
    return 0.5f * x * (1.0f + erff(x * 0.7071067811865475f));
}

// DPP lane shifts within 16-lane rows; invalid source lanes are masked off
// by the caller (x==0 / x==7 zero-pad), so bound_ctrl value is irrelevant.
__device__ __forceinline__ float dpp_shr1(float v) {  // lane L <- lane L-1
    return __int_as_float(__builtin_amdgcn_update_dpp(
        0, __float_as_int(v), 0x111, 0xf, 0xf, true));
}
__device__ __forceinline__ float dpp_shl1(float v) {  // lane L <- lane L+1
    return __int_as_float(__builtin_amdgcn_update_dpp(
        0, __float_as_int(v), 0x101, 0xf, 0xf, true));
}

// ---------------- CSR build over dst ----------------

__global__ __launch_bounds__(256) void zero_cnt_kernel(int* cnt, int n) {
    int i = blockIdx.x * 256 + threadIdx.x;
    if (i < n) cnt[i] = 0;
}

__global__ __launch_bounds__(256) void hist_kernel(const int* __restrict__ dst,
                                                   int* cnt, int ne) {
    int i = blockIdx.x * 256 + threadIdx.x;
    if (i < ne) atomicAdd(&cnt[dst[i]], 1);
}

__global__ __launch_bounds__(256) void scan_kernel(const int* __restrict__ cnt,
                                                   int* __restrict__ offs,
                                                   int* __restrict__ cursor,
                                                   int nn) {
    __shared__ int part[256];
    int t = threadIdx.x;
    int per = (nn + 255) >> 8;
    if (per > 32) per = 32;
    int base = t * per;
    int local[32];
    int sum = 0;
    for (int i = 0; i < per; i++) {
        int idx = base + i;
        int v = (idx < nn) ? cnt[idx] : 0;
        local[i] = sum;
        sum += v;
    }
    part[t] = sum;
    __syncthreads();
    int acc = sum;
    for (int d = 1; d < 256; d <<= 1) {
        int tv = (t >= d) ? part[t - d] : 0;
        __syncthreads();
        acc += tv;
        part[t] = acc;
        __syncthreads();
    }
    int excl = acc - sum;
    for (int i = 0; i < per; i++) {
        int idx = base + i;
        if (idx < nn) {
            int o = excl + local[i];
            offs[idx] = o;
            cursor[idx] = o;
        }
    }
    if (t == 255) offs[nn] = acc;
}

__global__ __launch_bounds__(256) void scatter_kernel(const int* __restrict__ dst,
                                                      int* cursor,
                                                      int* __restrict__ eid, int ne) {
    int i = blockIdx.x * 256 + threadIdx.x;
    if (i < ne) {
        int p = atomicAdd(&cursor[dst[i]], 1);
        eid[p] = i;
    }
}

// ---------------- per-node 3x3 conv ----------------
// lane = pixel (y*8+x); wave wv handles co = wv*8 .. wv*8+7 (wave-uniform).
// Weights read via wave-uniform global addresses -> scalar loads (broadcast
// via SGPR, no LDS, no bank conflicts). Input row taps: one stride-1
// ds_read_b32 per row; left/right neighbors via DPP lane shifts.
__global__ __launch_bounds__(256) void conv_kernel(const float* __restrict__ h,
                                                   const float* __restrict__ w,
                                                   float* __restrict__ convh) {
    __shared__ float sin_[CHW];  // 8 KB
    int n = blockIdx.x;
    const float4* h4 = (const float4*)(h + (size_t)n * CHW);
    float4* s4 = (float4*)sin_;
    s4[threadIdx.x] = h4[threadIdx.x];
    s4[threadIdx.x + 256] = h4[threadIdx.x + 256];
    __syncthreads();

    int lane = threadIdx.x & 63;
    int wv = __builtin_amdgcn_readfirstlane(threadIdx.x >> 6);  // uniform wave id
    int y = lane >> 3, x = lane & 7;
    const float* wbase = w + (size_t)wv * 8 * CCH * 9;  // uniform

    float acc[8];
#pragma unroll
    for (int i = 0; i < 8; i++) acc[i] = 0.f;
    bool x0 = (x == 0), x7 = (x == 7);

    for (int ci = 0; ci < CCH; ci++) {
        float Cc[3], L[3], R[3];
#pragma unroll
        for (int kh = 0; kh < 3; kh++) {
            int yy = y + kh - 1;
            bool val = (yy >= 0) && (yy <= 7);
            int yyc = val ? yy : 0;
            float c = sin_[ci * HWPIX + yyc * 8 + x];  // stride-1 across wave
            c = val ? c : 0.f;
            float l = dpp_shr1(c);
            float r = dpp_shl1(c);
            Cc[kh] = c;
            L[kh] = x0 ? 0.f : l;
            R[kh] = x7 ? 0.f : r;
        }
#pragma unroll
        for (int i = 0; i < 8; i++) {
            const float* wp = wbase + (i * CCH + ci) * 9;  // uniform -> s_load
            float a = acc[i];
#pragma unroll
            for (int kh = 0; kh < 3; kh++) {
                a = fmaf(wp[kh * 3 + 0], L[kh], a);
                a = fmaf(wp[kh * 3 + 1], Cc[kh], a);
                a = fmaf(wp[kh * 3 + 2], R[kh], a);
            }
            acc[i] = a;
        }
    }

    float* op = convh + (size_t)n * CHW;
#pragma unroll
    for (int i = 0; i < 8; i++)
        op[(wv * 8 + i) * HWPIX + lane] = acc[i];  // coalesced per co
}

// ---------------- gather + min/max + GELU epilogue ----------------
// 2 blocks per node; block handles half the CHW (1024 floats = 256 x float4).
// Software-pipelined: prefetch next edge's float4 while reducing current.
__global__ __launch_bounds__(256) void gather_max_kernel(
    const float* __restrict__ convh, const float* __restrict__ e,
    const int* __restrict__ src, const float* __restrict__ bias,
    const int* __restrict__ offs, const int* __restrict__ eid,
    float* __restrict__ out) {
    __shared__ int   s_src[EDGE_CHUNK];
    __shared__ float s_w[EDGE_CHUNK];
    int b = blockIdx.x;
    int n = b >> 1;
    int half = b & 1;
    int t = threadIdx.x;
    int base4 = half * 256 + t;  // float4 index within the node's CHW
    int beg = offs[n], end = offs[n + 1];

    const float NEG = -3.402823466e+38f, POS = 3.402823466e+38f;
    float mx0 = NEG, mx1 = NEG, mx2 = NEG, mx3 = NEG;
    float mn0 = POS, mn1 = POS, mn2 = POS, mn3 = POS;

    for (int cs = beg; cs < end; cs += EDGE_CHUNK) {
        int m = end - cs;
        if (m > EDGE_CHUNK) m = EDGE_CHUNK;
        __syncthreads();
        if (t < m) {
            int k = eid[cs + t];
            s_src[t] = src[k];
            s_w[t]   = e[k];
        }
        __syncthreads();

        float4 a = ((const float4*)(convh + (size_t)s_src[0] * CHW))[base4];
        float wg = s_w[0];
        for (int j = 0; j < m; j++) {
            float4 an = a;
            float wn = wg;
            if (j + 1 < m) {  // prefetch next edge
                an = ((const float4*)(convh + (size_t)s_src[j + 1] * CHW))[base4];
                wn = s_w[j + 1];
            }
            float p0 = wg * a.x, p1 = wg * a.y, p2 = wg * a.z, p3 = wg * a.w;
            mx0 = fmaxf(mx0, p0); mn0 = fminf(mn0, p0);
            mx1 = fmaxf(mx1, p1); mn1 = fminf(mn1, p1);
            mx2 = fmaxf(mx2, p2); mn2 = fminf(mn2, p2);
            mx3 = fmaxf(mx3, p3); mn3 = fminf(mn3, p3);
            a = an; wg = wn;
        }
    }

    // channel of element (half*1024 + 4t): ch = half*16 + (t>>4)
    float bb = bias[half * 16 + (t >> 4)];
    float4 r;
    r.x = fmaxf(gelu_f(mx0 + bb), gelu_f(mn0 + bb));
    r.y = fmaxf(gelu_f(mx1 + bb), gelu_f(mn1 + bb));
    r.z = fmaxf(gelu_f(mx2 + bb), gelu_f(mn2 + bb));
    r.w = fmaxf(gelu_f(mx3 + bb), gelu_f(mn3 + bb));

    ((float4*)(out + (size_t)n * CHW))[base4] = r;
}

extern "C" void kernel_launch(void* const* d_in, const int* in_sizes, int n_in,
                              void* d_out, int out_size, void* d_ws, size_t ws_size,
                              hipStream_t stream) {
    const float* h      = (const float*)d_in[0];
    const float* e      = (const float*)d_in[1];
    const float* conv_w = (const float*)d_in[2];
    const float* conv_b = (const float*)d_in[3];
    const int*   src    = (const int*)d_in[4];
    const int*   dst    = (const int*)d_in[5];
    int nn = in_sizes[0] / CHW;  // 5000
    int ne = in_sizes[1];        // 80000

    float* convh  = (float*)d_ws;                       // nn*CHW floats
    int*   cnt    = (int*)(convh + (size_t)nn * CHW);   // nn
    int*   offs   = cnt + nn;                           // nn+1
    int*   cursor = offs + nn + 1;                      // nn
    int*   eid    = cursor + nn;                        // ne

    zero_cnt_kernel<<<(nn + 255) / 256, 256, 0, stream>>>(cnt, nn);
    hist_kernel<<<(ne + 255) / 256, 256, 0, stream>>>(dst, cnt, ne);
    scan_kernel<<<1, 256, 0, stream>>>(cnt, offs, cursor, nn);
    scatter_kernel<<<(ne + 255) / 256, 256, 0, stream>>>(dst, cursor, eid, ne);
    conv_kernel<<<nn, 256, 0, stream>>>(h, conv_w, convh);
    gather_max_kernel<<<nn * 2, 256, 0, stream>>>(convh, e, src, conv_b, offs, eid,
                                                  (float*)d_out);
}

// Round 3
// 179.120 us; speedup vs baseline: 2.3264x; 1.5887x over previous
//
#include <hip/hip_runtime.h>
#include <math.h>

// N=5000 nodes, E=80000 edges, C=32, H=W=8  -> CHW = 2048 elems/node
#define CCH   32
#define HWPIX 64
#define CHW   2048
#define EDGE_CHUNK 64
#define HT_STRIDE 40   // shorts per pixel-row in LDS (16B-aligned, pad 8)
#define HT_NODE   2600 // 65 rows * 40 shorts (row 64 = zeros)

typedef __attribute__((ext_vector_type(8))) short bf16x8;
typedef __attribute__((ext_vector_type(4))) float f32x4;
typedef unsigned int uint_t;
typedef unsigned short ushort_t;

__device__ __forceinline__ float gelu_f(float x) {
    return 0.5f * x * (1.0f + erff(x * 0.7071067811865475f));
}

__device__ __forceinline__ ushort_t f2bf(float f) {  // RNE f32->bf16
    uint_t u = __float_as_uint(f);
    u += 0x7fffu + ((u >> 16) & 1u);
    return (ushort_t)(u >> 16);
}
__device__ __forceinline__ float bf2f(uint_t us) {  // exact bf16->f32
    return __uint_as_float(us << 16);
}

// ---------------- CSR build over dst ----------------

__global__ __launch_bounds__(256) void zero_cnt_kernel(int* cnt, int n) {
    int i = blockIdx.x * 256 + threadIdx.x;
    if (i < n) cnt[i] = 0;
}

__global__ __launch_bounds__(256) void hist_kernel(const int* __restrict__ dst,
                                                   int* cnt, int ne) {
    int i = blockIdx.x * 256 + threadIdx.x;
    if (i < ne) atomicAdd(&cnt[dst[i]], 1);
}

__global__ __launch_bounds__(256) void scan_kernel(const int* __restrict__ cnt,
                                                   int* __restrict__ offs,
                                                   int* __restrict__ cursor,
                                                   int nn) {
    __shared__ int part[256];
    int t = threadIdx.x;
    int per = (nn + 255) >> 8;
    if (per > 32) per = 32;
    int base = t * per;
    int local[32];
    int sum = 0;
    for (int i = 0; i < per; i++) {
        int idx = base + i;
        int v = (idx < nn) ? cnt[idx] : 0;
        local[i] = sum;
        sum += v;
    }
    part[t] = sum;
    __syncthreads();
    int acc = sum;
    for (int d = 1; d < 256; d <<= 1) {
        int tv = (t >= d) ? part[t - d] : 0;
        __syncthreads();
        acc += tv;
        part[t] = acc;
        __syncthreads();
    }
    int excl = acc - sum;
    for (int i = 0; i < per; i++) {
        int idx = base + i;
        if (idx < nn) {
            int o = excl + local[i];
            offs[idx] = o;
            cursor[idx] = o;
        }
    }
    if (t == 255) offs[nn] = acc;
}

__global__ __launch_bounds__(256) void scatter_kernel(const int* __restrict__ dst,
                                                      int* cursor,
                                                      int* __restrict__ eid, int ne) {
    int i = blockIdx.x * 256 + threadIdx.x;
    if (i < ne) {
        int p = atomicAdd(&cursor[dst[i]], 1);
        eid[p] = i;
    }
}

// ---------------- weight prep: f32 [co][ci][3][3] -> bf16 A-fragments ----------------
// A-frag layout for mfma_f32_16x16x32_bf16: A[m=lane&15][k=(lane>>4)*8+j], j=0..7.
// wfrag[(ch*9+tap)*64 + lane][j] = bf16(w[co=ch*16+(lane&15)][ci=(lane>>4)*8+j][tap])
__global__ __launch_bounds__(256) void prep_w_kernel(const float* __restrict__ w,
                                                     ushort_t* __restrict__ wfrag) {
    for (int idx = threadIdx.x; idx < 18 * 64; idx += 256) {
        int ch = idx / (9 * 64);
        int rem = idx % (9 * 64);
        int tap = rem / 64;
        int l = rem % 64;
        int co = ch * 16 + (l & 15);
        int g = l >> 4;
        for (int j = 0; j < 8; j++) {
            int ci = g * 8 + j;
            wfrag[(size_t)idx * 8 + j] = f2bf(w[(co * CCH + ci) * 9 + tap]);
        }
    }
}

// ---------------- per-node conv via bf16 MFMA ----------------
// Block = 2 nodes, 4 waves. Wave w: node (w>>1), co-half (w&1).
// LDS: Ht[node][pix][ci] bf16, row stride 40 shorts, row 64 = zeros (padding).
// Per wave: preload 9 A-frags (weights) into regs; loop 4 pixel-tiles x 9 taps,
// B-frag = one ds_read_b128 at shifted pixel row; 36 MFMAs total.
// Output convh: bf16, PIXEL-MAJOR [node][pix][co] so C-regs (4 consecutive co)
// pack into one 8-byte store.
__global__ __launch_bounds__(256) void conv_kernel(const float* __restrict__ h,
                                                   const ushort_t* __restrict__ wfrag,
                                                   ushort_t* __restrict__ convh) {
    __shared__ ushort_t Ht[2 * HT_NODE];  // 10400 B
    int t = threadIdx.x;
    int node0 = blockIdx.x * 2;

    // stage both nodes: pack ci-pairs -> transposed bf16 rows
    uint_t* Hd = (uint_t*)Ht;
#pragma unroll
    for (int nd = 0; nd < 2; nd++) {
        const float* hn = h + (size_t)(node0 + nd) * CHW;
#pragma unroll
        for (int it = 0; it < 4; it++) {
            int ci2 = it * 4 + (t >> 6);   // ci pair index 0..15
            int p = t & 63;                // pixel
            float a = hn[ci2 * 128 + p];
            float b = hn[ci2 * 128 + 64 + p];
            uint_t val = (uint_t)f2bf(a) | ((uint_t)f2bf(b) << 16);
            Hd[nd * (HT_NODE / 2) + p * (HT_STRIDE / 2) + ci2] = val;
        }
    }
    if (t < 40) {  // zero rows (pix=64) for both nodes
        Hd[0 * (HT_NODE / 2) + 64 * (HT_STRIDE / 2) + (t % 20) + (t / 20) * 0] = 0;
    }
    if (t >= 40 && t < 80) {
        Hd[1 * (HT_NODE / 2) + 64 * (HT_STRIDE / 2) + (t - 40) % 20] = 0;
    }
    // (first 20 of each needed; write all 20 dwords = 40 shorts)
    __syncthreads();

    int l = t & 63;
    int w = __builtin_amdgcn_readfirstlane(t >> 6);
    int nd = w >> 1;
    int ch = w & 1;
    int s = l & 15, g = l >> 4;
    int n = node0 + nd;

    bf16x8 A[9];
#pragma unroll
    for (int tap = 0; tap < 9; tap++)
        A[tap] = ((const bf16x8*)wfrag)[(ch * 9 + tap) * 64 + l];

    f32x4 C[4];
#pragma unroll
    for (int i = 0; i < 4; i++) C[i] = (f32x4){0.f, 0.f, 0.f, 0.f};

    const short* HtS = (const short*)(Ht + nd * HT_NODE);
#pragma unroll
    for (int tau = 0; tau < 4; tau++) {
        int p = tau * 16 + s;
        int y = p >> 3, x = p & 7;
#pragma unroll
        for (int tap = 0; tap < 9; tap++) {
            int dy = tap / 3 - 1, dx = tap % 3 - 1;
            int yy = y + dy, xx = x + dx;
            bool valid = (yy >= 0) & (yy < 8) & (xx >= 0) & (xx < 8);
            int pp = valid ? (yy * 8 + xx) : 64;
            bf16x8 B = *(const bf16x8*)&HtS[pp * HT_STRIDE + g * 8];
            C[tau] = __builtin_amdgcn_mfma_f32_16x16x32_bf16(A[tap], B, C[tau], 0, 0, 0);
        }
    }

    // C/D: col(pix within tile)=lane&15, row(co within half)=(lane>>4)*4+reg
    ushort_t* outn = convh + (size_t)n * CHW;
#pragma unroll
    for (int tau = 0; tau < 4; tau++) {
        uint_t lo = (uint_t)f2bf(C[tau][0]) | ((uint_t)f2bf(C[tau][1]) << 16);
        uint_t hi = (uint_t)f2bf(C[tau][2]) | ((uint_t)f2bf(C[tau][3]) << 16);
        uint2 v; v.x = lo; v.y = hi;
        // elem offset (shorts) = pix*32 + ch*16 + g*4  (pixel-major)
        *(uint2*)(outn + (tau * 16 + s) * 32 + ch * 16 + g * 4) = v;
    }
}

// ---------------- gather + min/max + GELU epilogue ----------------
// One block per node. Thread t owns 8 consecutive elems of the PIXEL-MAJOR
// convh: elem = t*8+i -> pix = t/4, co = (t&3)*8+i. uint4 load = 16B = 8 bf16.
__global__ __launch_bounds__(256) void gather_max_kernel(
    const ushort_t* __restrict__ convh, const float* __restrict__ e,
    const int* __restrict__ src, const float* __restrict__ bias,
    const int* __restrict__ offs, const int* __restrict__ eid,
    float* __restrict__ out) {
    __shared__ int   s_src[EDGE_CHUNK];
    __shared__ float s_w[EDGE_CHUNK];
    int n = blockIdx.x;
    int t = threadIdx.x;
    int beg = offs[n], end = offs[n + 1];

    const float NEG = -3.402823466e+38f, POS = 3.402823466e+38f;
    float mx[8], mn[8];
#pragma unroll
    for (int i = 0; i < 8; i++) { mx[i] = NEG; mn[i] = POS; }

    for (int cs = beg; cs < end; cs += EDGE_CHUNK) {
        int m = end - cs;
        if (m > EDGE_CHUNK) m = EDGE_CHUNK;
        __syncthreads();
        if (t < m) {
            int k = eid[cs + t];
            s_src[t] = src[k];
            s_w[t]   = e[k];
        }
        __syncthreads();

        uint4 a = ((const uint4*)(convh + (size_t)s_src[0] * CHW))[t];
        float wg = s_w[0];
        for (int j = 0; j < m; j++) {
            uint4 an = a;
            float wn = wg;
            if (j + 1 < m) {
                an = ((const uint4*)(convh + (size_t)s_src[j + 1] * CHW))[t];
                wn = s_w[j + 1];
            }
            float v0 = bf2f(a.x & 0xffffu), v1 = bf2f(a.x >> 16);
            float v2 = bf2f(a.y & 0xffffu), v3 = bf2f(a.y >> 16);
            float v4 = bf2f(a.z & 0xffffu), v5 = bf2f(a.z >> 16);
            float v6 = bf2f(a.w & 0xffffu), v7 = bf2f(a.w >> 16);
            float p0 = wg * v0, p1 = wg * v1, p2 = wg * v2, p3 = wg * v3;
            float p4 = wg * v4, p5 = wg * v5, p6 = wg * v6, p7 = wg * v7;
            mx[0] = fmaxf(mx[0], p0); mn[0] = fminf(mn[0], p0);
            mx[1] = fmaxf(mx[1], p1); mn[1] = fminf(mn[1], p1);
            mx[2] = fmaxf(mx[2], p2); mn[2] = fminf(mn[2], p2);
            mx[3] = fmaxf(mx[3], p3); mn[3] = fminf(mn[3], p3);
            mx[4] = fmaxf(mx[4], p4); mn[4] = fminf(mn[4], p4);
            mx[5] = fmaxf(mx[5], p5); mn[5] = fminf(mn[5], p5);
            mx[6] = fmaxf(mx[6], p6); mn[6] = fminf(mn[6], p6);
            mx[7] = fmaxf(mx[7], p7); mn[7] = fminf(mn[7], p7);
            a = an; wg = wn;
        }
    }

    // elem = t*8+i: pix = t/4, co = (t&3)*8+i. out is [co][pix] fp32.
    int pix = t >> 2;
    int cob = (t & 3) * 8;
    float* op = out + (size_t)n * CHW + pix;
#pragma unroll
    for (int i = 0; i < 8; i++) {
        float bb = bias[cob + i];
        float r = fmaxf(gelu_f(mx[i] + bb), gelu_f(mn[i] + bb));
        op[(size_t)(cob + i) * HWPIX] = r;
    }
}

extern "C" void kernel_launch(void* const* d_in, const int* in_sizes, int n_in,
                              void* d_out, int out_size, void* d_ws, size_t ws_size,
                              hipStream_t stream) {
    const float* h      = (const float*)d_in[0];
    const float* e      = (const float*)d_in[1];
    const float* conv_w = (const float*)d_in[2];
    const float* conv_b = (const float*)d_in[3];
    const int*   src    = (const int*)d_in[4];
    const int*   dst    = (const int*)d_in[5];
    int nn = in_sizes[0] / CHW;  // 5000
    int ne = in_sizes[1];        // 80000

    // ws layout: convh bf16 [nn*CHW shorts = 20.48 MB] | wfrag [18432 B] | ints
    ushort_t* convh = (ushort_t*)d_ws;
    ushort_t* wfrag = convh + (size_t)nn * CHW;
    int* cnt    = (int*)(wfrag + 18 * 64 * 8);
    int* offs   = cnt + nn;
    int* cursor = offs + nn + 1;
    int* eid    = cursor + nn;

    zero_cnt_kernel<<<(nn + 255) / 256, 256, 0, stream>>>(cnt, nn);
    hist_kernel<<<(ne + 255) / 256, 256, 0, stream>>>(dst, cnt, ne);
    scan_kernel<<<1, 256, 0, stream>>>(cnt, offs, cursor, nn);
    scatter_kernel<<<(ne + 255) / 256, 256, 0, stream>>>(dst, cursor, eid, ne);
    prep_w_kernel<<<1, 256, 0, stream>>>(conv_w, wfrag);
    conv_kernel<<<nn / 2, 256, 0, stream>>>(h, wfrag, convh);
    gather_max_kernel<<<nn, 256, 0, stream>>>(convh, e, src, conv_b, offs, eid,
                                              (float*)d_out);
}

// Round 4
// 177.046 us; speedup vs baseline: 2.3537x; 1.0117x over previous
//
#include <hip/hip_runtime.h>
#include <math.h>

// N=5000 nodes, E=80000 edges, C=32, H=W=8  -> CHW = 2048 elems/node
#define CCH   32
#define HWPIX 64
#define CHW   2048
#define EDGE_CHUNK 64
#define HT_STRIDE 40   // shorts per pixel-row in LDS (16B-aligned, pad 8)
#define HT_NODE   2600 // 65 rows * 40 shorts (row 64 = zeros)

typedef __attribute__((ext_vector_type(8))) short bf16x8;
typedef __attribute__((ext_vector_type(4))) float f32x4;
typedef unsigned int uint_t;
typedef unsigned short ushort_t;

__device__ __forceinline__ float gelu_f(float x) {
    return 0.5f * x * (1.0f + erff(x * 0.7071067811865475f));
}

__device__ __forceinline__ ushort_t f2bf(float f) {  // RNE f32->bf16
    uint_t u = __float_as_uint(f);
    u += 0x7fffu + ((u >> 16) & 1u);
    return (ushort_t)(u >> 16);
}
__device__ __forceinline__ float bf2f(uint_t us) {  // exact bf16->f32
    return __uint_as_float(us << 16);
}

// ---------------- CSR build over dst (cnt zeroed via hipMemsetAsync) ----------------

__global__ __launch_bounds__(256) void hist_kernel(const int* __restrict__ dst,
                                                   int* cnt, int ne) {
    int i = blockIdx.x * 256 + threadIdx.x;
    if (i < ne) atomicAdd(&cnt[dst[i]], 1);
}

__global__ __launch_bounds__(256) void scan_kernel(const int* __restrict__ cnt,
                                                   int* __restrict__ offs,
                                                   int* __restrict__ cursor,
                                                   int nn) {
    __shared__ int part[256];
    int t = threadIdx.x;
    int per = (nn + 255) >> 8;
    if (per > 32) per = 32;
    int base = t * per;
    int local[32];
    int sum = 0;
    for (int i = 0; i < per; i++) {
        int idx = base + i;
        int v = (idx < nn) ? cnt[idx] : 0;
        local[i] = sum;
        sum += v;
    }
    part[t] = sum;
    __syncthreads();
    int acc = sum;
    for (int d = 1; d < 256; d <<= 1) {
        int tv = (t >= d) ? part[t - d] : 0;
        __syncthreads();
        acc += tv;
        part[t] = acc;
        __syncthreads();
    }
    int excl = acc - sum;
    for (int i = 0; i < per; i++) {
        int idx = base + i;
        if (idx < nn) {
            int o = excl + local[i];
            offs[idx] = o;
            cursor[idx] = o;
        }
    }
    if (t == 255) offs[nn] = acc;
}

// Writes CSR-ordered src and weight arrays directly (no eid indirection).
__global__ __launch_bounds__(256) void scatter_kernel(const int* __restrict__ dst,
                                                      const int* __restrict__ src,
                                                      const float* __restrict__ e,
                                                      int* cursor,
                                                      int* __restrict__ srcA,
                                                      float* __restrict__ wA, int ne) {
    int i = blockIdx.x * 256 + threadIdx.x;
    if (i < ne) {
        int p = atomicAdd(&cursor[dst[i]], 1);
        srcA[p] = src[i];
        wA[p]   = e[i];
    }
}

// ---------------- weight prep: f32 [co][ci][3][3] -> bf16 A-fragments ----------------
// A-frag layout for mfma_f32_16x16x32_bf16: A[m=lane&15][k=(lane>>4)*8+j], j=0..7.
__global__ __launch_bounds__(256) void prep_w_kernel(const float* __restrict__ w,
                                                     ushort_t* __restrict__ wfrag) {
    for (int idx = threadIdx.x; idx < 18 * 64; idx += 256) {
        int ch = idx / (9 * 64);
        int rem = idx % (9 * 64);
        int tap = rem / 64;
        int l = rem % 64;
        int co = ch * 16 + (l & 15);
        int g = l >> 4;
        for (int j = 0; j < 8; j++) {
            int ci = g * 8 + j;
            wfrag[(size_t)idx * 8 + j] = f2bf(w[(co * CCH + ci) * 9 + tap]);
        }
    }
}

// ---------------- per-node conv via bf16 MFMA ----------------
// Block = 2 nodes, 4 waves. Wave w: node (w>>1), co-half (w&1).
// LDS: Ht[node][pix][ci] bf16, row stride 40 shorts, row 64 = zeros (padding).
// Output convh: bf16, PIXEL-MAJOR [node][pix][co].
__global__ __launch_bounds__(256) void conv_kernel(const float* __restrict__ h,
                                                   const ushort_t* __restrict__ wfrag,
                                                   ushort_t* __restrict__ convh) {
    __shared__ ushort_t Ht[2 * HT_NODE];  // 10400 B
    int t = threadIdx.x;
    int node0 = blockIdx.x * 2;

    uint_t* Hd = (uint_t*)Ht;
#pragma unroll
    for (int nd = 0; nd < 2; nd++) {
        const float* hn = h + (size_t)(node0 + nd) * CHW;
#pragma unroll
        for (int it = 0; it < 4; it++) {
            int ci2 = it * 4 + (t >> 6);   // ci pair index 0..15
            int p = t & 63;                // pixel
            float a = hn[ci2 * 128 + p];
            float b = hn[ci2 * 128 + 64 + p];
            uint_t val = (uint_t)f2bf(a) | ((uint_t)f2bf(b) << 16);
            Hd[nd * (HT_NODE / 2) + p * (HT_STRIDE / 2) + ci2] = val;
        }
    }
    if (t < 40) {
        Hd[0 * (HT_NODE / 2) + 64 * (HT_STRIDE / 2) + (t % 20)] = 0;
    }
    if (t >= 40 && t < 80) {
        Hd[1 * (HT_NODE / 2) + 64 * (HT_STRIDE / 2) + (t - 40) % 20] = 0;
    }
    __syncthreads();

    int l = t & 63;
    int w = __builtin_amdgcn_readfirstlane(t >> 6);
    int nd = w >> 1;
    int ch = w & 1;
    int s = l & 15, g = l >> 4;
    int n = node0 + nd;

    bf16x8 A[9];
#pragma unroll
    for (int tap = 0; tap < 9; tap++)
        A[tap] = ((const bf16x8*)wfrag)[(ch * 9 + tap) * 64 + l];

    f32x4 C[4];
#pragma unroll
    for (int i = 0; i < 4; i++) C[i] = (f32x4){0.f, 0.f, 0.f, 0.f};

    const short* HtS = (const short*)(Ht + nd * HT_NODE);
#pragma unroll
    for (int tau = 0; tau < 4; tau++) {
        int p = tau * 16 + s;
        int y = p >> 3, x = p & 7;
#pragma unroll
        for (int tap = 0; tap < 9; tap++) {
            int dy = tap / 3 - 1, dx = tap % 3 - 1;
            int yy = y + dy, xx = x + dx;
            bool valid = (yy >= 0) & (yy < 8) & (xx >= 0) & (xx < 8);
            int pp = valid ? (yy * 8 + xx) : 64;
            bf16x8 B = *(const bf16x8*)&HtS[pp * HT_STRIDE + g * 8];
            C[tau] = __builtin_amdgcn_mfma_f32_16x16x32_bf16(A[tap], B, C[tau], 0, 0, 0);
        }
    }

    ushort_t* outn = convh + (size_t)n * CHW;
#pragma unroll
    for (int tau = 0; tau < 4; tau++) {
        uint_t lo = (uint_t)f2bf(C[tau][0]) | ((uint_t)f2bf(C[tau][1]) << 16);
        uint_t hi = (uint_t)f2bf(C[tau][2]) | ((uint_t)f2bf(C[tau][3]) << 16);
        uint2 v; v.x = lo; v.y = hi;
        *(uint2*)(outn + (tau * 16 + s) * 32 + ch * 16 + g * 4) = v;
    }
}

// ---------------- gather + min/max + GELU epilogue ----------------
// One block per node, 4-deep software pipeline over edges (branchless body:
// chunk is padded to a multiple of 4 by DUPLICATING the last edge — duplicates
// are idempotent under min/max).
struct MinMax8 { float mx[8], mn[8]; };

__device__ __forceinline__ void reduce8(MinMax8& r, uint4 a, float wg) {
    float v0 = bf2f(a.x & 0xffffu), v1 = bf2f(a.x >> 16);
    float v2 = bf2f(a.y & 0xffffu), v3 = bf2f(a.y >> 16);
    float v4 = bf2f(a.z & 0xffffu), v5 = bf2f(a.z >> 16);
    float v6 = bf2f(a.w & 0xffffu), v7 = bf2f(a.w >> 16);
    float p0 = wg * v0, p1 = wg * v1, p2 = wg * v2, p3 = wg * v3;
    float p4 = wg * v4, p5 = wg * v5, p6 = wg * v6, p7 = wg * v7;
    r.mx[0] = fmaxf(r.mx[0], p0); r.mn[0] = fminf(r.mn[0], p0);
    r.mx[1] = fmaxf(r.mx[1], p1); r.mn[1] = fminf(r.mn[1], p1);
    r.mx[2] = fmaxf(r.mx[2], p2); r.mn[2] = fminf(r.mn[2], p2);
    r.mx[3] = fmaxf(r.mx[3], p3); r.mn[3] = fminf(r.mn[3], p3);
    r.mx[4] = fmaxf(r.mx[4], p4); r.mn[4] = fminf(r.mn[4], p4);
    r.mx[5] = fmaxf(r.mx[5], p5); r.mn[5] = fminf(r.mn[5], p5);
    r.mx[6] = fmaxf(r.mx[6], p6); r.mn[6] = fminf(r.mn[6], p6);
    r.mx[7] = fmaxf(r.mx[7], p7); r.mn[7] = fminf(r.mn[7], p7);
}

__global__ __launch_bounds__(256) void gather_max_kernel(
    const ushort_t* __restrict__ convh, const float* __restrict__ bias,
    const int* __restrict__ offs, const int* __restrict__ srcA,
    const float* __restrict__ wA, float* __restrict__ out) {
    __shared__ int   s_src[EDGE_CHUNK];
    __shared__ float s_w[EDGE_CHUNK];
    int n = blockIdx.x;
    int t = threadIdx.x;
    int beg = offs[n], end = offs[n + 1];

    const float NEG = -3.402823466e+38f, POS = 3.402823466e+38f;
    MinMax8 r;
#pragma unroll
    for (int i = 0; i < 8; i++) { r.mx[i] = NEG; r.mn[i] = POS; }

    for (int cs = beg; cs < end; cs += EDGE_CHUNK) {
        int m = end - cs;
        if (m > EDGE_CHUNK) m = EDGE_CHUNK;
        int mp = (m + 3) & ~3;  // padded count (pad = dup of last edge)
        __syncthreads();
        if (t < EDGE_CHUNK) {
            int idx = cs + t;
            if (idx >= end) idx = end - 1;  // duplicate last edge
            s_src[t] = srcA[idx];
            s_w[t]   = wA[idx];
        }
        __syncthreads();

        uint4 A0, A1, A2, A3, N0, N1, N2, N3;
        float W0, W1, W2, W3, U0, U1, U2, U3;
        A0 = ((const uint4*)(convh + (size_t)s_src[0] * CHW))[t]; W0 = s_w[0];
        A1 = ((const uint4*)(convh + (size_t)s_src[1] * CHW))[t]; W1 = s_w[1];
        A2 = ((const uint4*)(convh + (size_t)s_src[2] * CHW))[t]; W2 = s_w[2];
        A3 = ((const uint4*)(convh + (size_t)s_src[3] * CHW))[t]; W3 = s_w[3];

        int j = 0;
        while (true) {
            int jn = j + 4;
            bool more = (jn < mp);  // wave-uniform
            if (more) {
                N0 = ((const uint4*)(convh + (size_t)s_src[jn + 0] * CHW))[t]; U0 = s_w[jn + 0];
                N1 = ((const uint4*)(convh + (size_t)s_src[jn + 1] * CHW))[t]; U1 = s_w[jn + 1];
                N2 = ((const uint4*)(convh + (size_t)s_src[jn + 2] * CHW))[t]; U2 = s_w[jn + 2];
                N3 = ((const uint4*)(convh + (size_t)s_src[jn + 3] * CHW))[t]; U3 = s_w[jn + 3];
            }
            reduce8(r, A0, W0);
            reduce8(r, A1, W1);
            reduce8(r, A2, W2);
            reduce8(r, A3, W3);
            if (!more) break;
            A0 = N0; A1 = N1; A2 = N2; A3 = N3;
            W0 = U0; W1 = U1; W2 = U2; W3 = U3;
            j = jn;
        }
    }

    // elem = t*8+i: pix = t/4, co = (t&3)*8+i. out is [co][pix] fp32.
    int pix = t >> 2;
    int cob = (t & 3) * 8;
    float* op = out + (size_t)n * CHW + pix;
#pragma unroll
    for (int i = 0; i < 8; i++) {
        float bb = bias[cob + i];
        float v = fmaxf(gelu_f(r.mx[i] + bb), gelu_f(r.mn[i] + bb));
        op[(size_t)(cob + i) * HWPIX] = v;
    }
}

extern "C" void kernel_launch(void* const* d_in, const int* in_sizes, int n_in,
                              void* d_out, int out_size, void* d_ws, size_t ws_size,
                              hipStream_t stream) {
    const float* h      = (const float*)d_in[0];
    const float* e      = (const float*)d_in[1];
    const float* conv_w = (const float*)d_in[2];
    const float* conv_b = (const float*)d_in[3];
    const int*   src    = (const int*)d_in[4];
    const int*   dst    = (const int*)d_in[5];
    int nn = in_sizes[0] / CHW;  // 5000
    int ne = in_sizes[1];        // 80000

    // ws layout: convh bf16 | wfrag | cnt | offs | cursor | srcA | wA
    ushort_t* convh = (ushort_t*)d_ws;
    ushort_t* wfrag = convh + (size_t)nn * CHW;
    int*   cnt    = (int*)(wfrag + 18 * 64 * 8);
    int*   offs   = cnt + nn;
    int*   cursor = offs + nn + 1;
    int*   srcA   = cursor + nn;
    float* wA     = (float*)(srcA + ne);

    hipMemsetAsync(cnt, 0, (size_t)nn * sizeof(int), stream);
    hist_kernel<<<(ne + 255) / 256, 256, 0, stream>>>(dst, cnt, ne);
    scan_kernel<<<1, 256, 0, stream>>>(cnt, offs, cursor, nn);
    scatter_kernel<<<(ne + 255) / 256, 256, 0, stream>>>(dst, src, e, cursor,
                                                         srcA, wA, ne);
    prep_w_kernel<<<1, 256, 0, stream>>>(conv_w, wfrag);
    conv_kernel<<<nn / 2, 256, 0, stream>>>(h, wfrag, convh);
    gather_max_kernel<<<nn, 256, 0, stream>>>(convh, conv_b, offs, srcA, wA,
                                              (float*)d_out);
}

// Round 5
// 169.516 us; speedup vs baseline: 2.4582x; 1.0444x over previous
//
#include <hip/hip_runtime.h>
#include <math.h>

// N=5000 nodes, E=80000 edges, C=32, H=W=8  -> CHW = 2048 elems/node
#define CCH   32
#define HWPIX 64
#define CHW   2048
#define HT_STRIDE 40   // shorts per pixel-row in LDS (16B-aligned, pad 8)
#define HT_NODE   2600 // 65 rows * 40 shorts (row 64 = zeros)

typedef __attribute__((ext_vector_type(8))) short bf16x8;
typedef __attribute__((ext_vector_type(4))) float f32x4;
typedef unsigned int uint_t;
typedef unsigned short ushort_t;

__device__ __forceinline__ ushort_t f2bf(float f) {  // RNE f32->bf16
    uint_t u = __float_as_uint(f);
    u += 0x7fffu + ((u >> 16) & 1u);
    return (ushort_t)(u >> 16);
}

// tanh-form GELU: x * sigmoid(1.5957691216*(x + 0.044715 x^3)).
// |err vs exact erf-GELU| <= ~0.003 abs — within threshold budget.
__device__ __forceinline__ float fgelu(float x) {
    float x2 = x * x;
    float t = x * fmaf(0.0713548162726f, x2, 1.5957691216f);
    float ez = __expf(-t);
    return x * __builtin_amdgcn_rcpf(1.0f + ez);
}

// ---------------- CSR: hist (+ fused weight-frag prep) ----------------

__global__ __launch_bounds__(256) void hist_prep_kernel(
    const int* __restrict__ dst, int* cnt, int ne, int nhist,
    const float* __restrict__ w, ushort_t* __restrict__ wfrag) {
    int b = blockIdx.x;
    if (b < nhist) {
        int i = b * 256 + threadIdx.x;
        if (i < ne) atomicAdd(&cnt[dst[i]], 1);
    } else {
        // A-frag prep for mfma_f32_16x16x32_bf16:
        // A[m=lane&15][k=(lane>>4)*8+j]; wfrag[(ch*9+tap)*64+lane][j]
        for (int idx = threadIdx.x; idx < 18 * 64; idx += 256) {
            int ch = idx / (9 * 64);
            int rem = idx % (9 * 64);
            int tap = rem / 64;
            int l = rem % 64;
            int co = ch * 16 + (l & 15);
            int g = l >> 4;
            for (int j = 0; j < 8; j++) {
                int ci = g * 8 + j;
                wfrag[(size_t)idx * 8 + j] = f2bf(w[(co * CCH + ci) * 9 + tap]);
            }
        }
    }
}

__global__ __launch_bounds__(256) void scan_kernel(const int* __restrict__ cnt,
                                                   int* __restrict__ offs,
                                                   int* __restrict__ cursor,
                                                   int nn) {
    __shared__ int part[256];
    int t = threadIdx.x;
    int per = (nn + 255) >> 8;
    if (per > 32) per = 32;
    int base = t * per;
    int local[32];
    int sum = 0;
    for (int i = 0; i < per; i++) {
        int idx = base + i;
        int v = (idx < nn) ? cnt[idx] : 0;
        local[i] = sum;
        sum += v;
    }
    part[t] = sum;
    __syncthreads();
    int acc = sum;
    for (int d = 1; d < 256; d <<= 1) {
        int tv = (t >= d) ? part[t - d] : 0;
        __syncthreads();
        acc += tv;
        part[t] = acc;
        __syncthreads();
    }
    int excl = acc - sum;
    for (int i = 0; i < per; i++) {
        int idx = base + i;
        if (idx < nn) {
            int o = excl + local[i];
            offs[idx] = o;
            cursor[idx] = o;
        }
    }
    if (t == 255) offs[nn] = acc;
}

// ---------------- conv (bf16 MFMA) + fused CSR scatter ----------------
// Conv blocks [0,nconv): block = 2 nodes, 4 waves; output convh bf16
// PIXEL-MAJOR [node][pix][co]. Scatter blocks [nconv, nconv+nhist):
// CSR-ordered (src, weight) int2 pairs.
__global__ __launch_bounds__(256) void conv_scatter_kernel(
    const float* __restrict__ h, const ushort_t* __restrict__ wfrag,
    ushort_t* __restrict__ convh, int nconv,
    const int* __restrict__ dst, const int* __restrict__ src,
    const float* __restrict__ e, int* cursor, int2* __restrict__ swA, int ne) {
    __shared__ ushort_t Ht[2 * HT_NODE];  // 10400 B
    int b = blockIdx.x;
    int t = threadIdx.x;

    if (b >= nconv) {  // ---- scatter path (no barriers) ----
        int i = (b - nconv) * 256 + t;
        if (i < ne) {
            int p = atomicAdd(&cursor[dst[i]], 1);
            int2 v;
            v.x = src[i];
            v.y = __float_as_int(e[i]);
            swA[p] = v;
        }
        return;
    }

    // ---- conv path ----
    int node0 = b * 2;
    uint_t* Hd = (uint_t*)Ht;
#pragma unroll
    for (int nd = 0; nd < 2; nd++) {
        const float* hn = h + (size_t)(node0 + nd) * CHW;
#pragma unroll
        for (int it = 0; it < 4; it++) {
            int ci2 = it * 4 + (t >> 6);   // ci pair index 0..15
            int p = t & 63;                // pixel
            float a = hn[ci2 * 128 + p];
            float bb = hn[ci2 * 128 + 64 + p];
            uint_t val = (uint_t)f2bf(a) | ((uint_t)f2bf(bb) << 16);
            Hd[nd * (HT_NODE / 2) + p * (HT_STRIDE / 2) + ci2] = val;
        }
    }
    if (t < 40) Hd[0 * (HT_NODE / 2) + 64 * (HT_STRIDE / 2) + (t % 20)] = 0;
    if (t >= 40 && t < 80) Hd[1 * (HT_NODE / 2) + 64 * (HT_STRIDE / 2) + (t - 40) % 20] = 0;
    __syncthreads();

    int l = t & 63;
    int w = __builtin_amdgcn_readfirstlane(t >> 6);
    int nd = w >> 1;
    int ch = w & 1;
    int s = l & 15, g = l >> 4;
    int n = node0 + nd;

    bf16x8 A[9];
#pragma unroll
    for (int tap = 0; tap < 9; tap++)
        A[tap] = ((const bf16x8*)wfrag)[(ch * 9 + tap) * 64 + l];

    f32x4 C[4];
#pragma unroll
    for (int i = 0; i < 4; i++) C[i] = (f32x4){0.f, 0.f, 0.f, 0.f};

    const short* HtS = (const short*)(Ht + nd * HT_NODE);
#pragma unroll
    for (int tau = 0; tau < 4; tau++) {
        int p = tau * 16 + s;
        int y = p >> 3, x = p & 7;
#pragma unroll
        for (int tap = 0; tap < 9; tap++) {
            int dy = tap / 3 - 1, dx = tap % 3 - 1;
            int yy = y + dy, xx = x + dx;
            bool valid = (yy >= 0) & (yy < 8) & (xx >= 0) & (xx < 8);
            int pp = valid ? (yy * 8 + xx) : 64;
            bf16x8 B = *(const bf16x8*)&HtS[pp * HT_STRIDE + g * 8];
            C[tau] = __builtin_amdgcn_mfma_f32_16x16x32_bf16(A[tap], B, C[tau], 0, 0, 0);
        }
    }

    ushort_t* outn = convh + (size_t)n * CHW;
#pragma unroll
    for (int tau = 0; tau < 4; tau++) {
        uint_t lo = (uint_t)f2bf(C[tau][0]) | ((uint_t)f2bf(C[tau][1]) << 16);
        uint_t hi = (uint_t)f2bf(C[tau][2]) | ((uint_t)f2bf(C[tau][3]) << 16);
        uint2 v; v.x = lo; v.y = hi;
        *(uint2*)(outn + (tau * 16 + s) * 32 + ch * 16 + g * 4) = v;
    }
}

// ---------------- gather: wave-owns-half-node ----------------
// Block = 256 = 4 waves = 2 nodes (2 waves/node, half = 1024 elems each).
// Lane owns 16 elems as two uint4 groups (byte offsets l*16 and l*16+1024
// within the half). Per edge: one int2 broadcast (src, w) + 2 dwordx4 loads.
// 2-edge ping-pong; tail padded by duplicating the last edge (min/max-idempotent).
__device__ __forceinline__ void red8(float* mn, float* mx, uint4 q, float wg) {
    uint_t u0 = q.x, u1 = q.y, u2 = q.z, u3 = q.w;
    float v;
    v = wg * __uint_as_float(u0 << 16);          mn[0] = fminf(mn[0], v); mx[0] = fmaxf(mx[0], v);
    v = wg * __uint_as_float(u0 & 0xffff0000u);  mn[1] = fminf(mn[1], v); mx[1] = fmaxf(mx[1], v);
    v = wg * __uint_as_float(u1 << 16);          mn[2] = fminf(mn[2], v); mx[2] = fmaxf(mx[2], v);
    v = wg * __uint_as_float(u1 & 0xffff0000u);  mn[3] = fminf(mn[3], v); mx[3] = fmaxf(mx[3], v);
    v = wg * __uint_as_float(u2 << 16);          mn[4] = fminf(mn[4], v); mx[4] = fmaxf(mx[4], v);
    v = wg * __uint_as_float(u2 & 0xffff0000u);  mn[5] = fminf(mn[5], v); mx[5] = fmaxf(mx[5], v);
    v = wg * __uint_as_float(u3 << 16);          mn[6] = fminf(mn[6], v); mx[6] = fmaxf(mx[6], v);
    v = wg * __uint_as_float(u3 & 0xffff0000u);  mn[7] = fminf(mn[7], v); mx[7] = fmaxf(mx[7], v);
}

__global__ __launch_bounds__(256) void gather_max_kernel(
    const ushort_t* __restrict__ convh, const float* __restrict__ bias,
    const int* __restrict__ offs, const int2* __restrict__ swA,
    float* __restrict__ out) {
    int t = threadIdx.x;
    int l = t & 63;
    int w = t >> 6;
    int n = blockIdx.x * 2 + (w >> 1);
    int hf = w & 1;
    int beg = offs[n], end = offs[n + 1];
    int last = end - 1;

    const char* half_base = (const char*)convh + 2048 * hf + 16 * l;

    float mn[16], mx[16];
#pragma unroll
    for (int i = 0; i < 16; i++) { mn[i] = 3.402823466e+38f; mx[i] = -3.402823466e+38f; }

    // prologue: edges beg, min(beg+1,last)
    int jB = (beg < last) ? beg + 1 : last;
    int2 sA = swA[beg], sB = swA[jB];
    const char* pA = half_base + (size_t)sA.x * 4096;
    const char* pB = half_base + (size_t)sB.x * 4096;
    uint4 A0 = *(const uint4*)pA, A1 = *(const uint4*)(pA + 1024);
    uint4 B0 = *(const uint4*)pB, B1 = *(const uint4*)(pB + 1024);
    float wgA = __int_as_float(sA.y), wgB = __int_as_float(sB.y);

    for (int j = beg; j < end; j += 2) {
        int jC = (j + 2 <= last) ? j + 2 : last;
        int jD = (j + 3 <= last) ? j + 3 : last;
        int2 sC = swA[jC];
        int2 sD = swA[jD];
        red8(mn, mx, A0, wgA);
        red8(mn + 8, mx + 8, A1, wgA);
        const char* pC = half_base + (size_t)sC.x * 4096;
        A0 = *(const uint4*)pC; A1 = *(const uint4*)(pC + 1024);
        wgA = __int_as_float(sC.y);
        red8(mn, mx, B0, wgB);
        red8(mn + 8, mx + 8, B1, wgB);
        const char* pD = half_base + (size_t)sD.x * 4096;
        B0 = *(const uint4*)pD; B1 = *(const uint4*)(pD + 1024);
        wgB = __int_as_float(sD.y);
    }

    // epilogue: elem (within half) = jj*512 + l*8 + i
    //   pix = hf*32 + jj*16 + (l>>2), co = (l&3)*8 + i; out[n][co][pix] fp32
    const float4* b4 = (const float4*)(bias + (l & 3) * 8);
    float4 bLo = b4[0], bHi = b4[1];
    float bb[8] = {bLo.x, bLo.y, bLo.z, bLo.w, bHi.x, bHi.y, bHi.z, bHi.w};
    float* op = out + (size_t)n * CHW + (size_t)(l & 3) * 512 + hf * 32 + (l >> 2);
#pragma unroll
    for (int jj = 0; jj < 2; jj++) {
#pragma unroll
        for (int i = 0; i < 8; i++) {
            float xmx = mx[jj * 8 + i] + bb[i];
            float xmn = mn[jj * 8 + i] + bb[i];
            op[i * 64 + jj * 16] = fmaxf(fgelu(xmx), fgelu(xmn));
        }
    }
}

extern "C" void kernel_launch(void* const* d_in, const int* in_sizes, int n_in,
                              void* d_out, int out_size, void* d_ws, size_t ws_size,
                              hipStream_t stream) {
    const float* h      = (const float*)d_in[0];
    const float* e      = (const float*)d_in[1];
    const float* conv_w = (const float*)d_in[2];
    const float* conv_b = (const float*)d_in[3];
    const int*   src    = (const int*)d_in[4];
    const int*   dst    = (const int*)d_in[5];
    int nn = in_sizes[0] / CHW;  // 5000
    int ne = in_sizes[1];        // 80000

    // ws layout: convh bf16 | wfrag | cnt | offs(+pad) | cursor | swA(int2)
    ushort_t* convh = (ushort_t*)d_ws;
    ushort_t* wfrag = convh + (size_t)nn * CHW;
    int*   cnt    = (int*)(wfrag + 18 * 64 * 8);
    int*   offs   = cnt + nn;
    int*   cursor = offs + nn + 2;       // +1 pad int keeps swA 8B-aligned
    int2*  swA    = (int2*)(cursor + nn);

    int nhist = (ne + 255) / 256;  // 313
    int nconv = nn / 2;            // 2500

    hipMemsetAsync(cnt, 0, (size_t)nn * sizeof(int), stream);
    hist_prep_kernel<<<nhist + 1, 256, 0, stream>>>(dst, cnt, ne, nhist,
                                                    conv_w, wfrag);
    scan_kernel<<<1, 256, 0, stream>>>(cnt, offs, cursor, nn);
    conv_scatter_kernel<<<nconv + nhist, 256, 0, stream>>>(
        h, wfrag, convh, nconv, dst, src, e, cursor, swA, ne);
    gather_max_kernel<<<nn / 2, 256, 0, stream>>>(convh, conv_b, offs, swA,
                                                  (float*)d_out);
}

// Round 6
// 153.670 us; speedup vs baseline: 2.7117x; 1.1031x over previous
//
#include <hip/hip_runtime.h>
#include <math.h>

// N=5000 nodes, E=80000 edges, C=32, H=W=8  -> CHW = 2048 elems/node
#define CCH   32
#define HWPIX 64
#define CHW   2048
#define HT_STRIDE 40   // shorts per pixel-row in LDS (16B-aligned, pad 8)
#define HT_NODE   2600 // 65 rows * 40 shorts (row 64 = zeros)

typedef __attribute__((ext_vector_type(8))) short bf16x8;
typedef __attribute__((ext_vector_type(4))) float f32x4;
typedef unsigned int uint_t;
typedef unsigned short ushort_t;

__device__ __forceinline__ ushort_t f2bf(float f) {  // RNE f32->bf16
    uint_t u = __float_as_uint(f);
    u += 0x7fffu + ((u >> 16) & 1u);
    return (ushort_t)(u >> 16);
}

// tanh-form GELU: x * sigmoid(1.5957691216*(x + 0.044715 x^3)).
// |err vs exact erf-GELU| <= ~0.003 abs — within threshold budget.
__device__ __forceinline__ float fgelu(float x) {
    float x2 = x * x;
    float t = x * fmaf(0.0713548162726f, x2, 1.5957691216f);
    float ez = __expf(-t);
    return x * __builtin_amdgcn_rcpf(1.0f + ez);
}

// ---------------- CSR: hist (+ fused weight-frag prep) ----------------

__global__ __launch_bounds__(256) void hist_prep_kernel(
    const int* __restrict__ dst, int* cnt, int ne, int nhist,
    const float* __restrict__ w, ushort_t* __restrict__ wfrag) {
    int b = blockIdx.x;
    if (b < nhist) {
        int i = b * 256 + threadIdx.x;
        if (i < ne) atomicAdd(&cnt[dst[i]], 1);
    } else {
        // A-frag prep for mfma_f32_16x16x32_bf16:
        // A[m=lane&15][k=(lane>>4)*8+j]; wfrag[(ch*9+tap)*64+lane][j]
        for (int idx = threadIdx.x; idx < 18 * 64; idx += 256) {
            int ch = idx / (9 * 64);
            int rem = idx % (9 * 64);
            int tap = rem / 64;
            int l = rem % 64;
            int co = ch * 16 + (l & 15);
            int g = l >> 4;
            for (int j = 0; j < 8; j++) {
                int ci = g * 8 + j;
                wfrag[(size_t)idx * 8 + j] = f2bf(w[(co * CCH + ci) * 9 + tap]);
            }
        }
    }
}

__global__ __launch_bounds__(256) void scan_kernel(const int* __restrict__ cnt,
                                                   int* __restrict__ offs,
                                                   int* __restrict__ cursor,
                                                   int nn) {
    __shared__ int part[256];
    int t = threadIdx.x;
    int per = (nn + 255) >> 8;
    if (per > 32) per = 32;
    int base = t * per;
    int local[32];
    int sum = 0;
    for (int i = 0; i < per; i++) {
        int idx = base + i;
        int v = (idx < nn) ? cnt[idx] : 0;
        local[i] = sum;
        sum += v;
    }
    part[t] = sum;
    __syncthreads();
    int acc = sum;
    for (int d = 1; d < 256; d <<= 1) {
        int tv = (t >= d) ? part[t - d] : 0;
        __syncthreads();
        acc += tv;
        part[t] = acc;
        __syncthreads();
    }
    int excl = acc - sum;
    for (int i = 0; i < per; i++) {
        int idx = base + i;
        if (idx < nn) {
            int o = excl + local[i];
            offs[idx] = o;
            cursor[idx] = o;
        }
    }
    if (t == 255) offs[nn] = acc;
}

// ---------------- conv (bf16 MFMA) + fused CSR scatter ----------------
__global__ __launch_bounds__(256) void conv_scatter_kernel(
    const float* __restrict__ h, const ushort_t* __restrict__ wfrag,
    ushort_t* __restrict__ convh, int nconv,
    const int* __restrict__ dst, const int* __restrict__ src,
    const float* __restrict__ e, int* cursor, int2* __restrict__ swA, int ne) {
    __shared__ ushort_t Ht[2 * HT_NODE];  // 10400 B
    int b = blockIdx.x;
    int t = threadIdx.x;

    if (b >= nconv) {  // ---- scatter path (no barriers) ----
        int i = (b - nconv) * 256 + t;
        if (i < ne) {
            int p = atomicAdd(&cursor[dst[i]], 1);
            int2 v;
            v.x = src[i];
            v.y = __float_as_int(e[i]);
            swA[p] = v;
        }
        return;
    }

    // ---- conv path ----
    int node0 = b * 2;
    uint_t* Hd = (uint_t*)Ht;
#pragma unroll
    for (int nd = 0; nd < 2; nd++) {
        const float* hn = h + (size_t)(node0 + nd) * CHW;
#pragma unroll
        for (int it = 0; it < 4; it++) {
            int ci2 = it * 4 + (t >> 6);   // ci pair index 0..15
            int p = t & 63;                // pixel
            float a = hn[ci2 * 128 + p];
            float bb = hn[ci2 * 128 + 64 + p];
            uint_t val = (uint_t)f2bf(a) | ((uint_t)f2bf(bb) << 16);
            Hd[nd * (HT_NODE / 2) + p * (HT_STRIDE / 2) + ci2] = val;
        }
    }
    if (t < 40) Hd[0 * (HT_NODE / 2) + 64 * (HT_STRIDE / 2) + (t % 20)] = 0;
    if (t >= 40 && t < 80) Hd[1 * (HT_NODE / 2) + 64 * (HT_STRIDE / 2) + (t - 40) % 20] = 0;
    __syncthreads();

    int l = t & 63;
    int w = __builtin_amdgcn_readfirstlane(t >> 6);
    int nd = w >> 1;
    int ch = w & 1;
    int s = l & 15, g = l >> 4;
    int n = node0 + nd;

    bf16x8 A[9];
#pragma unroll
    for (int tap = 0; tap < 9; tap++)
        A[tap] = ((const bf16x8*)wfrag)[(ch * 9 + tap) * 64 + l];

    f32x4 C[4];
#pragma unroll
    for (int i = 0; i < 4; i++) C[i] = (f32x4){0.f, 0.f, 0.f, 0.f};

    const short* HtS = (const short*)(Ht + nd * HT_NODE);
#pragma unroll
    for (int tau = 0; tau < 4; tau++) {
        int p = tau * 16 + s;
        int y = p >> 3, x = p & 7;
#pragma unroll
        for (int tap = 0; tap < 9; tap++) {
            int dy = tap / 3 - 1, dx = tap % 3 - 1;
            int yy = y + dy, xx = x + dx;
            bool valid = (yy >= 0) & (yy < 8) & (xx >= 0) & (xx < 8);
            int pp = valid ? (yy * 8 + xx) : 64;
            bf16x8 B = *(const bf16x8*)&HtS[pp * HT_STRIDE + g * 8];
            C[tau] = __builtin_amdgcn_mfma_f32_16x16x32_bf16(A[tap], B, C[tau], 0, 0, 0);
        }
    }

    ushort_t* outn = convh + (size_t)n * CHW;
#pragma unroll
    for (int tau = 0; tau < 4; tau++) {
        uint_t lo = (uint_t)f2bf(C[tau][0]) | ((uint_t)f2bf(C[tau][1]) << 16);
        uint_t hi = (uint_t)f2bf(C[tau][2]) | ((uint_t)f2bf(C[tau][3]) << 16);
        uint2 v; v.x = lo; v.y = hi;
        *(uint2*)(outn + (tau * 16 + s) * 32 + ch * 16 + g * 4) = v;
    }
}

// ---------------- gather: wave-owns-QUARTER-node, XCD-localized ----------------
// Block = 4 waves = 4 nodes x 1 quarter. quarter q = blockIdx & 3, so with the
// round-robin blockIdx->XCD mapping (XCD = blockIdx % 8), each XCD's L2 only
// caches one 1KB/node quarter-slice of convh (5.1 MB) instead of all 20.5 MB.
// Lane owns 8 elems = one uint4 (16B) per edge. 4-edge pipeline; descriptors
// (src,w) prefetched two groups ahead so data reloads never stall on them.
// Tail padded by duplicating the last edge (min/max-idempotent).
__device__ __forceinline__ void red8(float* mn, float* mx, uint4 q, float wg) {
    uint_t u0 = q.x, u1 = q.y, u2 = q.z, u3 = q.w;
    float v;
    v = wg * __uint_as_float(u0 << 16);          mn[0] = fminf(mn[0], v); mx[0] = fmaxf(mx[0], v);
    v = wg * __uint_as_float(u0 & 0xffff0000u);  mn[1] = fminf(mn[1], v); mx[1] = fmaxf(mx[1], v);
    v = wg * __uint_as_float(u1 << 16);          mn[2] = fminf(mn[2], v); mx[2] = fmaxf(mx[2], v);
    v = wg * __uint_as_float(u1 & 0xffff0000u);  mn[3] = fminf(mn[3], v); mx[3] = fmaxf(mx[3], v);
    v = wg * __uint_as_float(u2 << 16);          mn[4] = fminf(mn[4], v); mx[4] = fmaxf(mx[4], v);
    v = wg * __uint_as_float(u2 & 0xffff0000u);  mn[5] = fminf(mn[5], v); mx[5] = fmaxf(mx[5], v);
    v = wg * __uint_as_float(u3 << 16);          mn[6] = fminf(mn[6], v); mx[6] = fmaxf(mx[6], v);
    v = wg * __uint_as_float(u3 & 0xffff0000u);  mn[7] = fminf(mn[7], v); mx[7] = fmaxf(mx[7], v);
}

__global__ __launch_bounds__(256) void gather_max_kernel(
    const ushort_t* __restrict__ convh, const float* __restrict__ bias,
    const int* __restrict__ offs, const int2* __restrict__ swA,
    float* __restrict__ out) {
    int t = threadIdx.x;
    int l = t & 63;
    int w = t >> 6;
    int b = blockIdx.x;
    int q = b & 3;                 // quarter — tied to XCD via blockIdx % 8
    int n = (b >> 2) * 4 + w;      // node
    int beg = offs[n], end = offs[n + 1];
    int last = end - 1;

    const char* qbase = (const char*)convh + 1024 * q + 16 * l;

    float mn[8], mx[8];
#pragma unroll
    for (int i = 0; i < 8; i++) { mn[i] = 3.402823466e+38f; mx[i] = -3.402823466e+38f; }

    // prologue: data group j..j+3, descriptor group j+4..j+7
    int j1 = (beg + 1 < last) ? beg + 1 : last;
    int j2 = (beg + 2 < last) ? beg + 2 : last;
    int j3 = (beg + 3 < last) ? beg + 3 : last;
    int2 d0 = swA[beg], d1 = swA[j1], d2 = swA[j2], d3 = swA[j3];
    uint4 Q0 = *(const uint4*)(qbase + (size_t)d0.x * 4096);
    uint4 Q1 = *(const uint4*)(qbase + (size_t)d1.x * 4096);
    uint4 Q2 = *(const uint4*)(qbase + (size_t)d2.x * 4096);
    uint4 Q3 = *(const uint4*)(qbase + (size_t)d3.x * 4096);
    float W0 = __int_as_float(d0.y), W1 = __int_as_float(d1.y);
    float W2 = __int_as_float(d2.y), W3 = __int_as_float(d3.y);
    int k0 = (beg + 4 < last) ? beg + 4 : last;
    int k1 = (beg + 5 < last) ? beg + 5 : last;
    int k2 = (beg + 6 < last) ? beg + 6 : last;
    int k3 = (beg + 7 < last) ? beg + 7 : last;
    int2 S0 = swA[k0], S1 = swA[k1], S2 = swA[k2], S3 = swA[k3];

    for (int j = beg; j < end; j += 4) {
        int m0 = (j + 8 < last) ? j + 8 : last;
        int m1 = (j + 9 < last) ? j + 9 : last;
        int m2 = (j + 10 < last) ? j + 10 : last;
        int m3 = (j + 11 < last) ? j + 11 : last;
        int2 N0 = swA[m0], N1 = swA[m1], N2 = swA[m2], N3 = swA[m3];
        red8(mn, mx, Q0, W0);
        Q0 = *(const uint4*)(qbase + (size_t)S0.x * 4096); W0 = __int_as_float(S0.y);
        red8(mn, mx, Q1, W1);
        Q1 = *(const uint4*)(qbase + (size_t)S1.x * 4096); W1 = __int_as_float(S1.y);
        red8(mn, mx, Q2, W2);
        Q2 = *(const uint4*)(qbase + (size_t)S2.x * 4096); W2 = __int_as_float(S2.y);
        red8(mn, mx, Q3, W3);
        Q3 = *(const uint4*)(qbase + (size_t)S3.x * 4096); W3 = __int_as_float(S3.y);
        S0 = N0; S1 = N1; S2 = N2; S3 = N3;
    }

    // epilogue: elem (within node) = q*512 + l*8 + i
    //   pix = q*16 + (l>>2), co = (l&3)*8 + i; out[n][co][pix] fp32
    const float4* b4 = (const float4*)(bias + (l & 3) * 8);
    float4 bLo = b4[0], bHi = b4[1];
    float bb[8] = {bLo.x, bLo.y, bLo.z, bLo.w, bHi.x, bHi.y, bHi.z, bHi.w};
    float* op = out + (size_t)n * CHW + (size_t)(l & 3) * 512 + q * 16 + (l >> 2);
#pragma unroll
    for (int i = 0; i < 8; i++) {
        op[i * 64] = fmaxf(fgelu(mx[i] + bb[i]), fgelu(mn[i] + bb[i]));
    }
}

extern "C" void kernel_launch(void* const* d_in, const int* in_sizes, int n_in,
                              void* d_out, int out_size, void* d_ws, size_t ws_size,
                              hipStream_t stream) {
    const float* h      = (const float*)d_in[0];
    const float* e      = (const float*)d_in[1];
    const float* conv_w = (const float*)d_in[2];
    const float* conv_b = (const float*)d_in[3];
    const int*   src    = (const int*)d_in[4];
    const int*   dst    = (const int*)d_in[5];
    int nn = in_sizes[0] / CHW;  // 5000
    int ne = in_sizes[1];        // 80000

    // ws layout: convh bf16 | wfrag | cnt | offs(+pad) | cursor | swA(int2)
    ushort_t* convh = (ushort_t*)d_ws;
    ushort_t* wfrag = convh + (size_t)nn * CHW;
    int*   cnt    = (int*)(wfrag + 18 * 64 * 8);
    int*   offs   = cnt + nn;
    int*   cursor = offs + nn + 2;       // +1 pad int keeps swA 8B-aligned
    int2*  swA    = (int2*)(cursor + nn);

    int nhist = (ne + 255) / 256;  // 313
    int nconv = nn / 2;            // 2500

    hipMemsetAsync(cnt, 0, (size_t)nn * sizeof(int), stream);
    hist_prep_kernel<<<nhist + 1, 256, 0, stream>>>(dst, cnt, ne, nhist,
                                                    conv_w, wfrag);
    scan_kernel<<<1, 256, 0, stream>>>(cnt, offs, cursor, nn);
    conv_scatter_kernel<<<nconv + nhist, 256, 0, stream>>>(
        h, wfrag, convh, nconv, dst, src, e, cursor, swA, ne);
    gather_max_kernel<<<nn, 256, 0, stream>>>(convh, conv_b, offs, swA,
                                              (float*)d_out);
}